// Round 9
// baseline (140.348 us; speedup 1.0000x reference)
//
#include <hip/hip_runtime.h>
#include <hip/hip_bf16.h>
#include <stdint.h>

// BS=16, T=16, N=512, C=128, E=128, OUT=256; P=8192, BT=256
// square[b,t,n,c] = feats[b, n*T+t, c]
// x1[e][bt][c] = sum_n square[n][c]*eig[e][n]          (bf16, ws)
// x3[bt][o][e] = sum_c x1[e][bt][c]*paramT[e][o][c]    (bf16, ws)
// out[bt][n][o] = relu(sum_e x3[bt][o][e]*eigT[n][e])  (f32, d_out)

typedef short bf16x8 __attribute__((ext_vector_type(8)));
typedef float f32x4 __attribute__((ext_vector_type(4)));

__device__ __forceinline__ ushort f2bf(float x) {
  __hip_bfloat16 h = __float2bfloat16(x);   // RNE, lowers to HW cvt on gfx950
  return *(ushort*)&h;
}

// ---------------- prep (merged): paramT + eig_bf + eigT ----------------
__global__ __launch_bounds__(256) void k_prep(const float* __restrict__ param,
                                              const float* __restrict__ eig,
                                              ushort* __restrict__ paramT,
                                              ushort* __restrict__ eig_bf,
                                              ushort* __restrict__ eigT) {
  int bid = blockIdx.x, tid = threadIdx.x;
  if (bid < 256) {
    int o = bid;
    int c = tid & 127, h = tid >> 7;
#pragma unroll 4
    for (int ee = 0; ee < 64; ++ee) {
      int e = h * 64 + ee;
      paramT[(size_t)e * 32768 + o * 128 + c] = f2bf(param[(size_t)o * 16384 + c * 128 + e]);
    }
  } else if (bid < 384) {
    int e = bid - 256;
    eig_bf[e * 512 + tid] = f2bf(eig[e * 512 + tid]);
    eig_bf[e * 512 + 256 + tid] = f2bf(eig[e * 512 + 256 + tid]);
  } else {
    int idx = bid - 384;                 // 0..127, 4 n-rows each
    int n = idx * 4 + (tid >> 6);
    int e0 = (tid & 63) * 2;
    ushort2 pk;
    pk.x = f2bf(eig[(size_t)e0 * 512 + n]);
    pk.y = f2bf(eig[(size_t)(e0 + 1) * 512 + n]);
    *(ushort2*)(eigT + n * 128 + e0) = pk;
  }
}

// ---------------- stage 1: x1[e][bt][c] ----------------
// grid 512 x 256 thr: (bt, c-half) -> 2 independent blocks/CU (cross-block HBM
// overlap). T14 async-split: next chunk's feats/eig loads issued into regs
// BEFORE the barrier; LDS-written next iteration. Packed b64 transpose staging.
__global__ __launch_bounds__(256) void k_stage1(const float* __restrict__ feats,
                                                const ushort* __restrict__ eig_bf,
                                                ushort* __restrict__ x1) {
  int bid = blockIdx.x;
  int bt = bid >> 1, ch = bid & 1;
  int b = bt >> 4, tt = bt & 15;
  __shared__ ushort As[64 * 72];   // [c-local 64][n-chunk 64 pad 72]
  __shared__ ushort Bs[128 * 72];  // [e 128][n-chunk 64 pad 72]
  int tid = threadIdx.x, l = tid & 63, w = tid >> 6;   // w 0..3
  int wr = (w & 1) * 32;   // c-local offset
  int wc = (w >> 1) * 64;  // e offset
  int lr = l & 15, lg = l >> 4;
  f32x4 acc[2][4] = {};
  const float* fbase = feats + (size_t)b * (8192 * 128) + (size_t)tt * 128 + ch * 64;
  int nq = l & 15;                     // n-quad (n = nq*4 + r)
  int c0 = ((l >> 4) + w * 4) * 4;     // c-local quad base 0..60
  int part = tid & 7, er = tid >> 3;   // Bs staging map

  // prologue: loads for chunk 0
  float4 va0, va1, va2, va3;
  uint4 vb[4];
  {
    const float* p = fbase + (size_t)(nq * 4) * 2048 + c0;
    va0 = *(const float4*)(p);
    va1 = *(const float4*)(p + 2048);
    va2 = *(const float4*)(p + 4096);
    va3 = *(const float4*)(p + 6144);
#pragma unroll
    for (int q = 0; q < 4; ++q)
      vb[q] = *(const uint4*)(eig_bf + (size_t)(er + q * 32) * 512 + part * 8);
  }
  float4 na0, na1, na2, na3;
  uint4 nb_[4];

  for (int nc = 0; nc < 8; ++nc) {
    // ---- write current regs to LDS (4x4 transpose + linear Bs) ----
    {
      const float* a0 = (const float*)&va0;
      const float* a1 = (const float*)&va1;
      const float* a2 = (const float*)&va2;
      const float* a3 = (const float*)&va3;
#pragma unroll
      for (int k = 0; k < 4; ++k) {
        ushort4 q;
        q.x = f2bf(a0[k]);
        q.y = f2bf(a1[k]);
        q.z = f2bf(a2[k]);
        q.w = f2bf(a3[k]);
        *(ushort4*)&As[(c0 + k) * 72 + nq * 4] = q;   // byte 144c+8nq: b64-aligned
      }
#pragma unroll
      for (int q = 0; q < 4; ++q)
        *(uint4*)&Bs[(er + q * 32) * 72 + part * 8] = vb[q];
    }
    // ---- T14: issue next chunk's loads; they fly during barrier + MFMA ----
    if (nc < 7) {
      int n0n = (nc + 1) * 64;
      const float* p = fbase + (size_t)(n0n + nq * 4) * 2048 + c0;
      na0 = *(const float4*)(p);
      na1 = *(const float4*)(p + 2048);
      na2 = *(const float4*)(p + 4096);
      na3 = *(const float4*)(p + 6144);
#pragma unroll
      for (int q = 0; q < 4; ++q)
        nb_[q] = *(const uint4*)(eig_bf + (size_t)(er + q * 32) * 512 + n0n + part * 8);
    }
    __syncthreads();
#pragma unroll
    for (int kk = 0; kk < 64; kk += 32) {
      bf16x8 af[2], bg[4];
#pragma unroll
      for (int fm = 0; fm < 2; ++fm)
        af[fm] = *(const bf16x8*)&As[(wr + fm * 16 + lr) * 72 + kk + lg * 8];
#pragma unroll
      for (int fn = 0; fn < 4; ++fn)
        bg[fn] = *(const bf16x8*)&Bs[(wc + fn * 16 + lr) * 72 + kk + lg * 8];
#pragma unroll
      for (int fm = 0; fm < 2; ++fm)
#pragma unroll
        for (int fn = 0; fn < 4; ++fn)
          acc[fm][fn] = __builtin_amdgcn_mfma_f32_16x16x32_bf16(af[fm], bg[fn], acc[fm][fn], 0, 0, 0);
    }
    __syncthreads();
    if (nc < 7) {
      va0 = na0; va1 = na1; va2 = na2; va3 = na3;
#pragma unroll
      for (int q = 0; q < 4; ++q) vb[q] = nb_[q];
    }
  }
  // epilogue: x1[e][bt][c] 8B packed
#pragma unroll
  for (int fm = 0; fm < 2; ++fm) {
    int c = ch * 64 + wr + fm * 16 + lg * 4;
#pragma unroll
    for (int fn = 0; fn < 4; ++fn) {
      int e = wc + fn * 16 + lr;
      ushort4 pk;
      pk.x = f2bf(acc[fm][fn][0]);
      pk.y = f2bf(acc[fm][fn][1]);
      pk.z = f2bf(acc[fm][fn][2]);
      pk.w = f2bf(acc[fm][fn][3]);
      *(ushort4*)(x1 + (size_t)e * 32768 + bt * 128 + c) = pk;
    }
  }
}

// ---------------- stage 2: x3[bt][o][e] ----------------
// grid 512: (btb 0..3) x (ob 0..3) x (ec 0..31), 4 e per block -> 2 blocks/CU.
__global__ __launch_bounds__(256) void k_stage2(const ushort* __restrict__ x1,
                                                const ushort* __restrict__ paramT,
                                                ushort* __restrict__ x3) {
  int bx = blockIdx.x;
  int btb = bx & 3, ob = (bx >> 2) & 3, ec = bx >> 4;
  int bt0 = btb * 64, o0 = ob * 64, e0 = ec * 4;
  __shared__ ushort As[64 * 136];  // [bt][c pad 136]
  __shared__ ushort Bs[64 * 136];  // [o][c pad 136]
  int tid = threadIdx.x, l = tid & 63, w = tid >> 6;
  int wbt = (w & 1) * 32, wo = (w >> 1) * 32;
  int lr = l & 15, lg = l >> 4;

  float res[2][2][4][4];
#pragma unroll
  for (int ei = 0; ei < 4; ++ei) {
    int e = e0 + ei;
    {
      int part = tid & 15, row = tid >> 4;
#pragma unroll
      for (int p = 0; p < 4; ++p) {
        int r_ = row + p * 16;
        uint4 va = *(const uint4*)(x1 + (size_t)e * 32768 + (bt0 + r_) * 128 + part * 8);
        *(uint4*)&As[r_ * 136 + part * 8] = va;
        uint4 vb = *(const uint4*)(paramT + (size_t)e * 32768 + (o0 + r_) * 128 + part * 8);
        *(uint4*)&Bs[r_ * 136 + part * 8] = vb;
      }
    }
    __syncthreads();
    f32x4 acc[2][2] = {};
#pragma unroll
    for (int kk = 0; kk < 128; kk += 32) {
      bf16x8 af[2], bg[2];
#pragma unroll
      for (int fm = 0; fm < 2; ++fm)
        af[fm] = *(const bf16x8*)&As[(wbt + fm * 16 + lr) * 136 + kk + lg * 8];
#pragma unroll
      for (int fn = 0; fn < 2; ++fn)
        bg[fn] = *(const bf16x8*)&Bs[(wo + fn * 16 + lr) * 136 + kk + lg * 8];
#pragma unroll
      for (int fm = 0; fm < 2; ++fm)
#pragma unroll
        for (int fn = 0; fn < 2; ++fn)
          acc[fm][fn] = __builtin_amdgcn_mfma_f32_16x16x32_bf16(af[fm], bg[fn], acc[fm][fn], 0, 0, 0);
    }
    __syncthreads();
#pragma unroll
    for (int fm = 0; fm < 2; ++fm)
#pragma unroll
      for (int fn = 0; fn < 2; ++fn)
#pragma unroll
        for (int r = 0; r < 4; ++r) res[fm][fn][r][ei] = acc[fm][fn][r];
  }
#pragma unroll
  for (int fm = 0; fm < 2; ++fm) {
    int btl = bt0 + wbt + fm * 16 + lg * 4;
#pragma unroll
    for (int fn = 0; fn < 2; ++fn) {
      int o = o0 + wo + fn * 16 + lr;
#pragma unroll
      for (int r = 0; r < 4; ++r) {
        ushort4 pk;
        pk.x = f2bf(res[fm][fn][r][0]);
        pk.y = f2bf(res[fm][fn][r][1]);
        pk.z = f2bf(res[fm][fn][r][2]);
        pk.w = f2bf(res[fm][fn][r][3]);
        *(ushort4*)(x3 + (size_t)(btl + r) * 32768 + o * 128 + e0) = pk;
      }
    }
  }
}

// ---------------- stage 3: out = relu(x3 @ eigT^T) ----------------
// grid 512 (bt, o-half). As (x3 o-slice) staged once. Bs (eigT n-chunk) staged
// per nb with T14 reg-prefetch: next chunk's loads issued before the MFMA phase.
__global__ __launch_bounds__(256) void k_stage3(const ushort* __restrict__ x3,
                                                const ushort* __restrict__ eigT,
                                                float* __restrict__ out) {
  int bx = blockIdx.x;
  int bt = bx >> 1, ob = bx & 1;
  int o0 = ob * 128;
  __shared__ ushort As[128 * 136];  // [o 128][e 128 pad 136]
  __shared__ ushort Bs[128 * 136];  // [n 128][e 128 pad 136]
  int tid = threadIdx.x, l = tid & 63, w = tid >> 6;
  int lr = l & 15, lg = l >> 4;
  int wo = (w & 1) * 64, wn = (w >> 1) * 64;
  const ushort* pa = x3 + (size_t)bt * 32768 + (size_t)o0 * 128;
  int part = tid & 15, row = tid >> 4;

  // stage As once: 128 rows x 256B
#pragma unroll
  for (int p = 0; p < 8; ++p) {
    int r_ = row + p * 16;
    uint4 va = *(const uint4*)(pa + (size_t)r_ * 128 + part * 8);
    *(uint4*)&As[r_ * 136 + part * 8] = va;
  }
  // prefetch Bs chunk 0 into regs
  uint4 rb[8], rbn[8];
#pragma unroll
  for (int p = 0; p < 8; ++p)
    rb[p] = *(const uint4*)(eigT + (size_t)(row + p * 16) * 128 + part * 8);

  for (int nb = 0; nb < 4; ++nb) {
    int n0 = nb * 128;
    __syncthreads();   // As ready (iter0) / prev Bs readers done
#pragma unroll
    for (int p = 0; p < 8; ++p)
      *(uint4*)&Bs[(row + p * 16) * 136 + part * 8] = rb[p];
    if (nb < 3) {
      int n0n = n0 + 128;
#pragma unroll
      for (int p = 0; p < 8; ++p)
        rbn[p] = *(const uint4*)(eigT + (size_t)(n0n + row + p * 16) * 128 + part * 8);
    }
    __syncthreads();
    f32x4 acc[4][4] = {};
#pragma unroll
    for (int kk = 0; kk < 128; kk += 32) {
      bf16x8 af[4], bg[4];
#pragma unroll
      for (int fm = 0; fm < 4; ++fm)
        af[fm] = *(const bf16x8*)&As[(wo + fm * 16 + lr) * 136 + kk + lg * 8];
#pragma unroll
      for (int fn = 0; fn < 4; ++fn)
        bg[fn] = *(const bf16x8*)&Bs[(wn + fn * 16 + lr) * 136 + kk + lg * 8];
#pragma unroll
      for (int fm = 0; fm < 4; ++fm)
#pragma unroll
        for (int fn = 0; fn < 4; ++fn)
          acc[fm][fn] = __builtin_amdgcn_mfma_f32_16x16x32_bf16(af[fm], bg[fn], acc[fm][fn], 0, 0, 0);
    }
#pragma unroll
    for (int fm = 0; fm < 4; ++fm) {
      int o = o0 + wo + fm * 16 + lg * 4;
#pragma unroll
      for (int fn = 0; fn < 4; ++fn) {
        int n = n0 + wn + fn * 16 + lr;
        float4 v;
        v.x = fmaxf(acc[fm][fn][0], 0.f);
        v.y = fmaxf(acc[fm][fn][1], 0.f);
        v.z = fmaxf(acc[fm][fn][2], 0.f);
        v.w = fmaxf(acc[fm][fn][3], 0.f);
        *(float4*)(out + (size_t)bt * 131072 + (size_t)n * 256 + o) = v;
      }
    }
    if (nb < 3) {
#pragma unroll
      for (int p = 0; p < 8; ++p) rb[p] = rbn[p];
    }
  }
}

extern "C" void kernel_launch(void* const* d_in, const int* in_sizes, int n_in,
                              void* d_out, int out_size, void* d_ws, size_t ws_size,
                              hipStream_t stream) {
  const float* feats = (const float*)d_in[0];
  const float* eig = (const float*)d_in[4];
  const float* param = (const float*)d_in[5];
  float* out = (float*)d_out;

  char* ws = (char*)d_ws;
  ushort* paramT = (ushort*)(ws);                 // 8 MB  [e][o][c]
  ushort* eig_bf = (ushort*)(ws + 8388608);       // 128 KB [e][n]
  ushort* eigT   = (ushort*)(ws + 8519680);       // 128 KB [n][e]
  ushort* x1     = (ushort*)(ws + 8650752);       // 8 MB  [e][bt][c]
  ushort* x3     = (ushort*)(ws + 17039360);      // 16 MB [bt][o][e]

  hipLaunchKernelGGL(k_prep, dim3(512), dim3(256), 0, stream, param, eig, paramT, eig_bf, eigT);
  hipLaunchKernelGGL(k_stage1, dim3(512), dim3(256), 0, stream, feats, eig_bf, x1);
  hipLaunchKernelGGL(k_stage2, dim3(512), dim3(256), 0, stream, x1, paramT, x3);
  hipLaunchKernelGGL(k_stage3, dim3(512), dim3(256), 0, stream, x3, eigT, out);
}

// Round 10
// 80.783 us; speedup vs baseline: 1.7373x; 1.7373x over previous
//
#include <hip/hip_runtime.h>
#include <hip/hip_bf16.h>
#include <stdint.h>

// BS=16, T=16, N=512, C=128, E=128, OUT=256; P=8192, BT=256
// square[b,t,n,c] = feats[b, n*T+t, c]
// x1[e][bt][c] = sum_n square[n][c]*eig[e][n]          (bf16, ws)
// x3[bt][o][e] = sum_c x1[e][bt][c]*paramT[e][o][c]    (bf16, ws)
// out[bt][n][o] = relu(sum_e x3[bt][o][e]*eigT[n][e])  (f32, d_out)

typedef short bf16x8 __attribute__((ext_vector_type(8)));
typedef float f32x4 __attribute__((ext_vector_type(4)));

__device__ __forceinline__ ushort f2bf(float x) {
  __hip_bfloat16 h = __float2bfloat16(x);   // RNE, lowers to HW cvt on gfx950
  return *(ushort*)&h;
}

// ---------------- prep (merged): paramT + eig_bf + eigT ----------------
__global__ __launch_bounds__(256) void k_prep(const float* __restrict__ param,
                                              const float* __restrict__ eig,
                                              ushort* __restrict__ paramT,
                                              ushort* __restrict__ eig_bf,
                                              ushort* __restrict__ eigT) {
  int bid = blockIdx.x, tid = threadIdx.x;
  if (bid < 256) {
    int o = bid;
    int c = tid & 127, h = tid >> 7;
#pragma unroll 4
    for (int ee = 0; ee < 64; ++ee) {
      int e = h * 64 + ee;
      paramT[(size_t)e * 32768 + o * 128 + c] = f2bf(param[(size_t)o * 16384 + c * 128 + e]);
    }
  } else if (bid < 384) {
    int e = bid - 256;
    eig_bf[e * 512 + tid] = f2bf(eig[e * 512 + tid]);
    eig_bf[e * 512 + 256 + tid] = f2bf(eig[e * 512 + 256 + tid]);
  } else {
    int idx = bid - 384;                 // 0..127, 4 n-rows each
    int n = idx * 4 + (tid >> 6);
    int e0 = (tid & 63) * 2;
    ushort2 pk;
    pk.x = f2bf(eig[(size_t)e0 * 512 + n]);
    pk.y = f2bf(eig[(size_t)(e0 + 1) * 512 + n]);
    *(ushort2*)(eigT + n * 128 + e0) = pk;
  }
}

// ---------------- stage 1: x1[e][bt][c] ----------------
// 256 blocks x 512 threads (8 waves: 4-way c x 2-way e). Packed b64 transpose
// staging; 2 waves/SIMD hide MFMA + barrier latency.
__global__ __launch_bounds__(512) void k_stage1(const float* __restrict__ feats,
                                                const ushort* __restrict__ eig_bf,
                                                ushort* __restrict__ x1) {
  int bt = blockIdx.x;
  int b = bt >> 4, tt = bt & 15;
  __shared__ ushort As[128 * 72];  // [c][n-chunk 64, pad 72]
  __shared__ ushort Bs[128 * 72];  // [e][n-chunk 64, pad 72]
  int tid = threadIdx.x, l = tid & 63, w = tid >> 6;   // w 0..7
  int wr = (w & 3) * 32;   // c offset (4-way)
  int wc = (w >> 2) * 64;  // e offset (2-way)
  int lr = l & 15, lg = l >> 4;
  f32x4 acc[2][4] = {};
  const float* fbase = feats + (size_t)b * (8192 * 128) + (size_t)tt * 128;

  int nq = l & 15;   // n-quad (n = nq*4 + r)
  int cb = l >> 4;   // 0..3

  for (int nc = 0; nc < 8; ++nc) {
    int n0 = nc * 64;
    // ---- stage A: transpose feats chunk into As[c][n] via packed b64 writes ----
    {
      int c0 = (cb + w * 4) * 4;   // c-quad base: (cb + w*4) in 0..31 covers all c
      const float* p = fbase + (size_t)(n0 + nq * 4) * 2048 + c0;
      float4 v0 = *(const float4*)(p);
      float4 v1 = *(const float4*)(p + 2048);
      float4 v2 = *(const float4*)(p + 4096);
      float4 v3 = *(const float4*)(p + 6144);
      const float* a0 = (const float*)&v0;
      const float* a1 = (const float*)&v1;
      const float* a2 = (const float*)&v2;
      const float* a3 = (const float*)&v3;
#pragma unroll
      for (int k = 0; k < 4; ++k) {
        ushort4 q;
        q.x = f2bf(a0[k]);
        q.y = f2bf(a1[k]);
        q.z = f2bf(a2[k]);
        q.w = f2bf(a3[k]);
        *(ushort4*)&As[(c0 + k) * 72 + nq * 4] = q;   // byte 144c+8nq: b64-aligned
      }
    }
    // ---- stage B: eig rows (linear copy, 2 passes with 512 threads) ----
    {
      int part = tid & 7;
      int er = tid >> 3;   // 0..63
#pragma unroll
      for (int p = 0; p < 2; ++p) {
        int e = er + p * 64;
        uint4 v = *(const uint4*)(eig_bf + (size_t)e * 512 + n0 + part * 8);
        *(uint4*)&Bs[e * 72 + part * 8] = v;
      }
    }
    __syncthreads();
#pragma unroll
    for (int kk = 0; kk < 64; kk += 32) {
      bf16x8 af[2], bg[4];
#pragma unroll
      for (int fm = 0; fm < 2; ++fm)
        af[fm] = *(const bf16x8*)&As[(wr + fm * 16 + lr) * 72 + kk + lg * 8];
#pragma unroll
      for (int fn = 0; fn < 4; ++fn)
        bg[fn] = *(const bf16x8*)&Bs[(wc + fn * 16 + lr) * 72 + kk + lg * 8];
#pragma unroll
      for (int fm = 0; fm < 2; ++fm)
#pragma unroll
        for (int fn = 0; fn < 4; ++fn)
          acc[fm][fn] = __builtin_amdgcn_mfma_f32_16x16x32_bf16(af[fm], bg[fn], acc[fm][fn], 0, 0, 0);
    }
    __syncthreads();
  }
#pragma unroll
  for (int fm = 0; fm < 2; ++fm) {
    int c = wr + fm * 16 + lg * 4;
#pragma unroll
    for (int fn = 0; fn < 4; ++fn) {
      int e = wc + fn * 16 + lr;
      ushort4 pk;
      pk.x = f2bf(acc[fm][fn][0]);
      pk.y = f2bf(acc[fm][fn][1]);
      pk.z = f2bf(acc[fm][fn][2]);
      pk.w = f2bf(acc[fm][fn][3]);
      *(ushort4*)(x1 + (size_t)e * 32768 + bt * 128 + c) = pk;
    }
  }
}

// ---------------- stage 2: x3[bt][o][e] ----------------
// grid 512: (btb 0..3) x (ob 0..3) x (ec 0..31), 4 e per block -> 2 blocks/CU.
__global__ __launch_bounds__(256) void k_stage2(const ushort* __restrict__ x1,
                                                const ushort* __restrict__ paramT,
                                                ushort* __restrict__ x3) {
  int bx = blockIdx.x;
  int btb = bx & 3, ob = (bx >> 2) & 3, ec = bx >> 4;
  int bt0 = btb * 64, o0 = ob * 64, e0 = ec * 4;
  __shared__ ushort As[64 * 136];  // [bt][c pad 136]
  __shared__ ushort Bs[64 * 136];  // [o][c pad 136]
  int tid = threadIdx.x, l = tid & 63, w = tid >> 6;
  int wbt = (w & 1) * 32, wo = (w >> 1) * 32;
  int lr = l & 15, lg = l >> 4;

  float res[2][2][4][4];
#pragma unroll
  for (int ei = 0; ei < 4; ++ei) {
    int e = e0 + ei;
    {
      int part = tid & 15, row = tid >> 4;
#pragma unroll
      for (int p = 0; p < 4; ++p) {
        int r_ = row + p * 16;
        uint4 va = *(const uint4*)(x1 + (size_t)e * 32768 + (bt0 + r_) * 128 + part * 8);
        *(uint4*)&As[r_ * 136 + part * 8] = va;
        uint4 vb = *(const uint4*)(paramT + (size_t)e * 32768 + (o0 + r_) * 128 + part * 8);
        *(uint4*)&Bs[r_ * 136 + part * 8] = vb;
      }
    }
    __syncthreads();
    f32x4 acc[2][2] = {};
#pragma unroll
    for (int kk = 0; kk < 128; kk += 32) {
      bf16x8 af[2], bg[2];
#pragma unroll
      for (int fm = 0; fm < 2; ++fm)
        af[fm] = *(const bf16x8*)&As[(wbt + fm * 16 + lr) * 136 + kk + lg * 8];
#pragma unroll
      for (int fn = 0; fn < 2; ++fn)
        bg[fn] = *(const bf16x8*)&Bs[(wo + fn * 16 + lr) * 136 + kk + lg * 8];
#pragma unroll
      for (int fm = 0; fm < 2; ++fm)
#pragma unroll
        for (int fn = 0; fn < 2; ++fn)
          acc[fm][fn] = __builtin_amdgcn_mfma_f32_16x16x32_bf16(af[fm], bg[fn], acc[fm][fn], 0, 0, 0);
    }
    __syncthreads();
#pragma unroll
    for (int fm = 0; fm < 2; ++fm)
#pragma unroll
      for (int fn = 0; fn < 2; ++fn)
#pragma unroll
        for (int r = 0; r < 4; ++r) res[fm][fn][r][ei] = acc[fm][fn][r];
  }
#pragma unroll
  for (int fm = 0; fm < 2; ++fm) {
    int btl = bt0 + wbt + fm * 16 + lg * 4;
#pragma unroll
    for (int fn = 0; fn < 2; ++fn) {
      int o = o0 + wo + fn * 16 + lr;
#pragma unroll
      for (int r = 0; r < 4; ++r) {
        ushort4 pk;
        pk.x = f2bf(res[fm][fn][r][0]);
        pk.y = f2bf(res[fm][fn][r][1]);
        pk.z = f2bf(res[fm][fn][r][2]);
        pk.w = f2bf(res[fm][fn][r][3]);
        *(ushort4*)(x3 + (size_t)(btl + r) * 32768 + o * 128 + e0) = pk;
      }
    }
  }
}

// ---------------- stage 3: out = relu(x3 @ eigT^T) ----------------
// grid 512 (bt 0..255, o-half 0..1). A-tile (x3 o-slice, full e=128) staged ONCE;
// loop 4 n-chunks of 128 staging Bs from eigT. x3 read traffic 64->16 MB.
__global__ __launch_bounds__(256) void k_stage3(const ushort* __restrict__ x3,
                                                const ushort* __restrict__ eigT,
                                                float* __restrict__ out) {
  int bx = blockIdx.x;
  int bt = bx >> 1, ob = bx & 1;
  int o0 = ob * 128;
  __shared__ ushort As[128 * 136];  // [o 128][e 128 pad 136]
  __shared__ ushort Bs[128 * 136];  // [n 128][e 128 pad 136]
  int tid = threadIdx.x, l = tid & 63, w = tid >> 6;
  int lr = l & 15, lg = l >> 4;
  int wo = (w & 1) * 64, wn = (w >> 1) * 64;
  const ushort* pa = x3 + (size_t)bt * 32768 + (size_t)o0 * 128;

  // stage As once: 128 rows x 256B
  {
    int part = tid & 15, row = tid >> 4;  // 16 rows/pass, 8 passes
#pragma unroll
    for (int p = 0; p < 8; ++p) {
      int r_ = row + p * 16;
      uint4 va = *(const uint4*)(pa + (size_t)r_ * 128 + part * 8);
      *(uint4*)&As[r_ * 136 + part * 8] = va;
    }
  }

  for (int nb = 0; nb < 4; ++nb) {
    int n0 = nb * 128;
    __syncthreads();   // protect Bs from previous iteration's readers
    {
      int part = tid & 15, row = tid >> 4;
#pragma unroll
      for (int p = 0; p < 8; ++p) {
        int r_ = row + p * 16;
        uint4 vb = *(const uint4*)(eigT + (size_t)(n0 + r_) * 128 + part * 8);
        *(uint4*)&Bs[r_ * 136 + part * 8] = vb;
      }
    }
    __syncthreads();
    f32x4 acc[4][4] = {};
#pragma unroll
    for (int kk = 0; kk < 128; kk += 32) {
      bf16x8 af[4], bg[4];
#pragma unroll
      for (int fm = 0; fm < 4; ++fm)
        af[fm] = *(const bf16x8*)&As[(wo + fm * 16 + lr) * 136 + kk + lg * 8];
#pragma unroll
      for (int fn = 0; fn < 4; ++fn)
        bg[fn] = *(const bf16x8*)&Bs[(wn + fn * 16 + lr) * 136 + kk + lg * 8];
#pragma unroll
      for (int fm = 0; fm < 4; ++fm)
#pragma unroll
        for (int fn = 0; fn < 4; ++fn)
          acc[fm][fn] = __builtin_amdgcn_mfma_f32_16x16x32_bf16(af[fm], bg[fn], acc[fm][fn], 0, 0, 0);
    }
#pragma unroll
    for (int fm = 0; fm < 4; ++fm) {
      int o = o0 + wo + fm * 16 + lg * 4;
#pragma unroll
      for (int fn = 0; fn < 4; ++fn) {
        int n = n0 + wn + fn * 16 + lr;
        float4 v;
        v.x = fmaxf(acc[fm][fn][0], 0.f);
        v.y = fmaxf(acc[fm][fn][1], 0.f);
        v.z = fmaxf(acc[fm][fn][2], 0.f);
        v.w = fmaxf(acc[fm][fn][3], 0.f);
        *(float4*)(out + (size_t)bt * 131072 + (size_t)n * 256 + o) = v;
      }
    }
  }
}

extern "C" void kernel_launch(void* const* d_in, const int* in_sizes, int n_in,
                              void* d_out, int out_size, void* d_ws, size_t ws_size,
                              hipStream_t stream) {
  const float* feats = (const float*)d_in[0];
  const float* eig = (const float*)d_in[4];
  const float* param = (const float*)d_in[5];
  float* out = (float*)d_out;

  char* ws = (char*)d_ws;
  ushort* paramT = (ushort*)(ws);                 // 8 MB  [e][o][c]
  ushort* eig_bf = (ushort*)(ws + 8388608);       // 128 KB [e][n]
  ushort* eigT   = (ushort*)(ws + 8519680);       // 128 KB [n][e]
  ushort* x1     = (ushort*)(ws + 8650752);       // 8 MB  [e][bt][c]
  ushort* x3     = (ushort*)(ws + 17039360);      // 16 MB [bt][o][e]

  hipLaunchKernelGGL(k_prep, dim3(512), dim3(256), 0, stream, param, eig, paramT, eig_bf, eigT);
  hipLaunchKernelGGL(k_stage1, dim3(256), dim3(512), 0, stream, feats, eig_bf, x1);
  hipLaunchKernelGGL(k_stage2, dim3(512), dim3(256), 0, stream, x1, paramT, x3);
  hipLaunchKernelGGL(k_stage3, dim3(512), dim3(256), 0, stream, x3, eigT, out);  // 256 bt x 2 o-halves
}

// Round 11
// 78.397 us; speedup vs baseline: 1.7902x; 1.0304x over previous
//
#include <hip/hip_runtime.h>
#include <hip/hip_bf16.h>
#include <stdint.h>

// BS=16, T=16, N=512, C=128, E=128, OUT=256; P=8192, BT=256
// square[b,t,n,c] = feats[b, n*T+t, c]
// x1[e][bt][c] = sum_n square[n][c]*eig[e][n]          (bf16, ws)
// x3[bt][o][e] = sum_c x1[e][bt][c]*paramT[e][o][c]    (bf16, ws)
// out[bt][n][o] = relu(sum_e x3[bt][o][e]*eigT[n][e])  (f32, d_out)

typedef short bf16x8 __attribute__((ext_vector_type(8)));
typedef float f32x4 __attribute__((ext_vector_type(4)));

__device__ __forceinline__ ushort f2bf(float x) {
  __hip_bfloat16 h = __float2bfloat16(x);   // RNE, lowers to HW cvt on gfx950
  return *(ushort*)&h;
}

// ---------------- prep (merged): paramT + eig_bf + eigT ----------------
__global__ __launch_bounds__(256) void k_prep(const float* __restrict__ param,
                                              const float* __restrict__ eig,
                                              ushort* __restrict__ paramT,
                                              ushort* __restrict__ eig_bf,
                                              ushort* __restrict__ eigT) {
  int bid = blockIdx.x, tid = threadIdx.x;
  if (bid < 256) {
    int o = bid;
    int c = tid & 127, h = tid >> 7;
#pragma unroll 4
    for (int ee = 0; ee < 64; ++ee) {
      int e = h * 64 + ee;
      paramT[(size_t)e * 32768 + o * 128 + c] = f2bf(param[(size_t)o * 16384 + c * 128 + e]);
    }
  } else if (bid < 384) {
    int e = bid - 256;
    eig_bf[e * 512 + tid] = f2bf(eig[e * 512 + tid]);
    eig_bf[e * 512 + 256 + tid] = f2bf(eig[e * 512 + 256 + tid]);
  } else {
    int idx = bid - 384;                 // 0..127, 4 n-rows each
    int n = idx * 4 + (tid >> 6);
    int e0 = (tid & 63) * 2;
    ushort2 pk;
    pk.x = f2bf(eig[(size_t)e0 * 512 + n]);
    pk.y = f2bf(eig[(size_t)(e0 + 1) * 512 + n]);
    *(ushort2*)(eigT + n * 128 + e0) = pk;
  }
}

// ---------------- stage 1: x1[e][bt][c] ----------------
// grid 512 x 512 thr: (bt, c-half) -> 2 independent blocks/CU, 16 waves/CU.
// Role-split staging: threads 0-255 transpose feats (4x4 packed b64 writes),
// threads 256-511 copy eig rows. Cross-block overlap hides HBM latency.
__global__ __launch_bounds__(512) void k_stage1(const float* __restrict__ feats,
                                                const ushort* __restrict__ eig_bf,
                                                ushort* __restrict__ x1) {
  int bid = blockIdx.x;
  int bt = bid >> 1, ch = bid & 1;
  int b = bt >> 4, tt = bt & 15;
  __shared__ ushort As[64 * 72];   // [c-local 64][n-chunk 64, pad 72]
  __shared__ ushort Bs[128 * 72];  // [e 128][n-chunk 64, pad 72]
  int tid = threadIdx.x, l = tid & 63, w = tid >> 6;   // w 0..7
  int wr = (w & 1) * 32;   // c-local offset (2-way)
  int wc = (w >> 1) * 32;  // e offset (4-way)
  int lr = l & 15, lg = l >> 4;
  f32x4 acc[2][2] = {};
  const float* fbase = feats + (size_t)b * (8192 * 128) + (size_t)tt * 128 + ch * 64;

  // staging roles
  int nq = tid & 15;             // A-role: n-quad
  int cq = (tid >> 4) & 15;      // A-role: c-quad (c0 = cq*4, 0..60)
  int lb = tid - 256;            // B-role local id
  int partB = lb & 7, erB = lb >> 3;

  for (int nc = 0; nc < 8; ++nc) {
    int n0 = nc * 64;
    if (tid < 256) {
      // ---- A: transpose 4x4 feats into As[c][n], packed b64 writes ----
      int c0 = cq * 4;
      const float* p = fbase + (size_t)(n0 + nq * 4) * 2048 + c0;
      float4 v0 = *(const float4*)(p);
      float4 v1 = *(const float4*)(p + 2048);
      float4 v2 = *(const float4*)(p + 4096);
      float4 v3 = *(const float4*)(p + 6144);
      const float* a0 = (const float*)&v0;
      const float* a1 = (const float*)&v1;
      const float* a2 = (const float*)&v2;
      const float* a3 = (const float*)&v3;
#pragma unroll
      for (int k = 0; k < 4; ++k) {
        ushort4 q;
        q.x = f2bf(a0[k]);
        q.y = f2bf(a1[k]);
        q.z = f2bf(a2[k]);
        q.w = f2bf(a3[k]);
        *(ushort4*)&As[(c0 + k) * 72 + nq * 4] = q;   // byte 144c+8nq: b64-aligned
      }
    } else {
      // ---- B: eig rows linear copy (128 rows x 128B, 64B/thread) ----
#pragma unroll
      for (int p = 0; p < 4; ++p) {
        int e = erB + p * 32;
        uint4 v = *(const uint4*)(eig_bf + (size_t)e * 512 + n0 + partB * 8);
        *(uint4*)&Bs[e * 72 + partB * 8] = v;
      }
    }
    __syncthreads();
#pragma unroll
    for (int kk = 0; kk < 64; kk += 32) {
      bf16x8 af[2], bg[2];
#pragma unroll
      for (int fm = 0; fm < 2; ++fm)
        af[fm] = *(const bf16x8*)&As[(wr + fm * 16 + lr) * 72 + kk + lg * 8];
#pragma unroll
      for (int fn = 0; fn < 2; ++fn)
        bg[fn] = *(const bf16x8*)&Bs[(wc + fn * 16 + lr) * 72 + kk + lg * 8];
#pragma unroll
      for (int fm = 0; fm < 2; ++fm)
#pragma unroll
        for (int fn = 0; fn < 2; ++fn)
          acc[fm][fn] = __builtin_amdgcn_mfma_f32_16x16x32_bf16(af[fm], bg[fn], acc[fm][fn], 0, 0, 0);
    }
    __syncthreads();
  }
  // epilogue: x1[e][bt][c] 8B packed
#pragma unroll
  for (int fm = 0; fm < 2; ++fm) {
    int c = ch * 64 + wr + fm * 16 + lg * 4;
#pragma unroll
    for (int fn = 0; fn < 2; ++fn) {
      int e = wc + fn * 16 + lr;
      ushort4 pk;
      pk.x = f2bf(acc[fm][fn][0]);
      pk.y = f2bf(acc[fm][fn][1]);
      pk.z = f2bf(acc[fm][fn][2]);
      pk.w = f2bf(acc[fm][fn][3]);
      *(ushort4*)(x1 + (size_t)e * 32768 + bt * 128 + c) = pk;
    }
  }
}

// ---------------- stage 2: x3[bt][o][e] ----------------
// grid 512: (btb 0..3) x (ob 0..3) x (ec 0..31), 4 e per block -> 2 blocks/CU.
__global__ __launch_bounds__(256) void k_stage2(const ushort* __restrict__ x1,
                                                const ushort* __restrict__ paramT,
                                                ushort* __restrict__ x3) {
  int bx = blockIdx.x;
  int btb = bx & 3, ob = (bx >> 2) & 3, ec = bx >> 4;
  int bt0 = btb * 64, o0 = ob * 64, e0 = ec * 4;
  __shared__ ushort As[64 * 136];  // [bt][c pad 136]
  __shared__ ushort Bs[64 * 136];  // [o][c pad 136]
  int tid = threadIdx.x, l = tid & 63, w = tid >> 6;
  int wbt = (w & 1) * 32, wo = (w >> 1) * 32;
  int lr = l & 15, lg = l >> 4;

  float res[2][2][4][4];
#pragma unroll
  for (int ei = 0; ei < 4; ++ei) {
    int e = e0 + ei;
    {
      int part = tid & 15, row = tid >> 4;
#pragma unroll
      for (int p = 0; p < 4; ++p) {
        int r_ = row + p * 16;
        uint4 va = *(const uint4*)(x1 + (size_t)e * 32768 + (bt0 + r_) * 128 + part * 8);
        *(uint4*)&As[r_ * 136 + part * 8] = va;
        uint4 vb = *(const uint4*)(paramT + (size_t)e * 32768 + (o0 + r_) * 128 + part * 8);
        *(uint4*)&Bs[r_ * 136 + part * 8] = vb;
      }
    }
    __syncthreads();
    f32x4 acc[2][2] = {};
#pragma unroll
    for (int kk = 0; kk < 128; kk += 32) {
      bf16x8 af[2], bg[2];
#pragma unroll
      for (int fm = 0; fm < 2; ++fm)
        af[fm] = *(const bf16x8*)&As[(wbt + fm * 16 + lr) * 136 + kk + lg * 8];
#pragma unroll
      for (int fn = 0; fn < 2; ++fn)
        bg[fn] = *(const bf16x8*)&Bs[(wo + fn * 16 + lr) * 136 + kk + lg * 8];
#pragma unroll
      for (int fm = 0; fm < 2; ++fm)
#pragma unroll
        for (int fn = 0; fn < 2; ++fn)
          acc[fm][fn] = __builtin_amdgcn_mfma_f32_16x16x32_bf16(af[fm], bg[fn], acc[fm][fn], 0, 0, 0);
    }
    __syncthreads();
#pragma unroll
    for (int fm = 0; fm < 2; ++fm)
#pragma unroll
      for (int fn = 0; fn < 2; ++fn)
#pragma unroll
        for (int r = 0; r < 4; ++r) res[fm][fn][r][ei] = acc[fm][fn][r];
  }
#pragma unroll
  for (int fm = 0; fm < 2; ++fm) {
    int btl = bt0 + wbt + fm * 16 + lg * 4;
#pragma unroll
    for (int fn = 0; fn < 2; ++fn) {
      int o = o0 + wo + fn * 16 + lr;
#pragma unroll
      for (int r = 0; r < 4; ++r) {
        ushort4 pk;
        pk.x = f2bf(res[fm][fn][r][0]);
        pk.y = f2bf(res[fm][fn][r][1]);
        pk.z = f2bf(res[fm][fn][r][2]);
        pk.w = f2bf(res[fm][fn][r][3]);
        *(ushort4*)(x3 + (size_t)(btl + r) * 32768 + o * 128 + e0) = pk;
      }
    }
  }
}

// ---------------- stage 3: out = relu(x3 @ eigT^T) ----------------
// grid 512 (bt 0..255, o-half 0..1). A-tile (x3 o-slice, full e=128) staged ONCE;
// loop 4 n-chunks of 128 staging Bs from eigT. x3 read traffic 64->16 MB.
__global__ __launch_bounds__(256) void k_stage3(const ushort* __restrict__ x3,
                                                const ushort* __restrict__ eigT,
                                                float* __restrict__ out) {
  int bx = blockIdx.x;
  int bt = bx >> 1, ob = bx & 1;
  int o0 = ob * 128;
  __shared__ ushort As[128 * 136];  // [o 128][e 128 pad 136]
  __shared__ ushort Bs[128 * 136];  // [n 128][e 128 pad 136]
  int tid = threadIdx.x, l = tid & 63, w = tid >> 6;
  int lr = l & 15, lg = l >> 4;
  int wo = (w & 1) * 64, wn = (w >> 1) * 64;
  const ushort* pa = x3 + (size_t)bt * 32768 + (size_t)o0 * 128;

  // stage As once: 128 rows x 256B
  {
    int part = tid & 15, row = tid >> 4;  // 16 rows/pass, 8 passes
#pragma unroll
    for (int p = 0; p < 8; ++p) {
      int r_ = row + p * 16;
      uint4 va = *(const uint4*)(pa + (size_t)r_ * 128 + part * 8);
      *(uint4*)&As[r_ * 136 + part * 8] = va;
    }
  }

  for (int nb = 0; nb < 4; ++nb) {
    int n0 = nb * 128;
    __syncthreads();   // protect Bs from previous iteration's readers
    {
      int part = tid & 15, row = tid >> 4;
#pragma unroll
      for (int p = 0; p < 8; ++p) {
        int r_ = row + p * 16;
        uint4 vb = *(const uint4*)(eigT + (size_t)(n0 + r_) * 128 + part * 8);
        *(uint4*)&Bs[r_ * 136 + part * 8] = vb;
      }
    }
    __syncthreads();
    f32x4 acc[4][4] = {};
#pragma unroll
    for (int kk = 0; kk < 128; kk += 32) {
      bf16x8 af[4], bg[4];
#pragma unroll
      for (int fm = 0; fm < 4; ++fm)
        af[fm] = *(const bf16x8*)&As[(wo + fm * 16 + lr) * 136 + kk + lg * 8];
#pragma unroll
      for (int fn = 0; fn < 4; ++fn)
        bg[fn] = *(const bf16x8*)&Bs[(wn + fn * 16 + lr) * 136 + kk + lg * 8];
#pragma unroll
      for (int fm = 0; fm < 4; ++fm)
#pragma unroll
        for (int fn = 0; fn < 4; ++fn)
          acc[fm][fn] = __builtin_amdgcn_mfma_f32_16x16x32_bf16(af[fm], bg[fn], acc[fm][fn], 0, 0, 0);
    }
#pragma unroll
    for (int fm = 0; fm < 4; ++fm) {
      int o = o0 + wo + fm * 16 + lg * 4;
#pragma unroll
      for (int fn = 0; fn < 4; ++fn) {
        int n = n0 + wn + fn * 16 + lr;
        float4 v;
        v.x = fmaxf(acc[fm][fn][0], 0.f);
        v.y = fmaxf(acc[fm][fn][1], 0.f);
        v.z = fmaxf(acc[fm][fn][2], 0.f);
        v.w = fmaxf(acc[fm][fn][3], 0.f);
        *(float4*)(out + (size_t)bt * 131072 + (size_t)n * 256 + o) = v;
      }
    }
  }
}

extern "C" void kernel_launch(void* const* d_in, const int* in_sizes, int n_in,
                              void* d_out, int out_size, void* d_ws, size_t ws_size,
                              hipStream_t stream) {
  const float* feats = (const float*)d_in[0];
  const float* eig = (const float*)d_in[4];
  const float* param = (const float*)d_in[5];
  float* out = (float*)d_out;

  char* ws = (char*)d_ws;
  ushort* paramT = (ushort*)(ws);                 // 8 MB  [e][o][c]
  ushort* eig_bf = (ushort*)(ws + 8388608);       // 128 KB [e][n]
  ushort* eigT   = (ushort*)(ws + 8519680);       // 128 KB [n][e]
  ushort* x1     = (ushort*)(ws + 8650752);       // 8 MB  [e][bt][c]
  ushort* x3     = (ushort*)(ws + 17039360);      // 16 MB [bt][o][e]

  hipLaunchKernelGGL(k_prep, dim3(512), dim3(256), 0, stream, param, eig, paramT, eig_bf, eigT);
  hipLaunchKernelGGL(k_stage1, dim3(512), dim3(512), 0, stream, feats, eig_bf, x1);
  hipLaunchKernelGGL(k_stage2, dim3(512), dim3(256), 0, stream, x1, paramT, x3);
  hipLaunchKernelGGL(k_stage3, dim3(512), dim3(256), 0, stream, x3, eigT, out);
}